// Round 1
// baseline (400.996 us; speedup 1.0000x reference)
//
#include <hip/hip_runtime.h>

#define NCH 32

// Gather/compaction: out[c, k] = in[c, idx[k]] for c in [0,32), k in [0, n_kept).
// Each thread owns 4 consecutive k values: 1 coalesced int4 idx load,
// then per channel 4 gathered scalar loads + 1 coalesced float4 store.
__global__ __launch_bounds__(256) void octree_depad_kernel(
    const float* __restrict__ in,
    const int* __restrict__ idx,
    float* __restrict__ out,
    int n_kept, int n_pad) {
    int k4 = blockIdx.x * blockDim.x + threadIdx.x;
    int total4 = n_kept >> 2;   // n_kept divisible by 4 handled below; tail guarded

    if (k4 < total4) {
        int k = k4 << 2;
        // coalesced 16B index load
        int4 iv = *reinterpret_cast<const int4*>(idx + k);
        long long i0 = iv.x, i1 = iv.y, i2 = iv.z, i3 = iv.w;

        #pragma unroll 8
        for (int c = 0; c < NCH; ++c) {
            const float* src = in + (size_t)c * (size_t)n_pad;
            float4 v;
            v.x = src[i0];
            v.y = src[i1];
            v.z = src[i2];
            v.w = src[i3];
            *reinterpret_cast<float4*>(out + (size_t)c * (size_t)n_kept + k) = v;
        }
    }

    // Tail: handle n_kept % 4 leftovers with the first few threads of block 0.
    int tail_start = total4 << 2;
    int n_tail = n_kept - tail_start;
    if (n_tail > 0 && blockIdx.x == 0 && (int)threadIdx.x < n_tail) {
        int k = tail_start + threadIdx.x;
        long long s = idx[k];
        #pragma unroll 8
        for (int c = 0; c < NCH; ++c) {
            out[(size_t)c * (size_t)n_kept + k] = in[(size_t)c * (size_t)n_pad + s];
        }
    }
}

extern "C" void kernel_launch(void* const* d_in, const int* in_sizes, int n_in,
                              void* d_out, int out_size, void* d_ws, size_t ws_size,
                              hipStream_t stream) {
    const float* in  = (const float*)d_in[0];
    const int*   idx = (const int*)d_in[1];
    float*       out = (float*)d_out;

    int n_kept = in_sizes[1];            // 1048576
    int n_pad  = in_sizes[0] / NCH;      // 2097152

    int total4 = (n_kept + 3) >> 2;
    int block  = 256;
    int grid   = (total4 + block - 1) / block;

    octree_depad_kernel<<<grid, block, 0, stream>>>(in, idx, out, n_kept, n_pad);
}

// Round 2
// 400.331 us; speedup vs baseline: 1.0017x; 1.0017x over previous
//
#include <hip/hip_runtime.h>

#define NCH 32
#define BLOCK 256
#define K_TILE 1024
#define PER_T (K_TILE / BLOCK)     // 4 kept elements per thread
#define LDS_FLOATS 3072            // 12 KB; expected span ~2048, slack ~1024

// out[c, k] = in[c, idx[k]].  idx sorted, ~50% dense.
// Per block: tile of K_TILE kept indices. Cooperative coalesced float4 load of
// the contiguous input span covering the tile into LDS, then gather from LDS.
__global__ __launch_bounds__(BLOCK) void octree_depad_lds(
    const float* __restrict__ in,
    const int* __restrict__ idx,
    float* __restrict__ out,
    int n_kept, int n_pad) {
    __shared__ float lds[LDS_FLOATS];

    const int t  = threadIdx.x;
    const int k0 = blockIdx.x * K_TILE;
    const int kend  = min(k0 + K_TILE, n_kept);
    const int klast = kend - 1;

    // Span of input covered by this tile (idx sorted).
    const int first = idx[k0];         // broadcast, L2-hot
    const int last  = idx[klast];
    const int base  = first & ~3;      // align to float4
    const int span  = last - base + 1;

    // Per-thread kept positions (interleaved: lane t owns k0 + j*BLOCK + t,
    // so LDS-gather lane stride ~2 floats -> near-conflict-free, stores coalesced).
    int  kk[PER_T];
    int  loc[PER_T];
    bool valid[PER_T];
#pragma unroll
    for (int j = 0; j < PER_T; ++j) {
        int k = k0 + j * BLOCK + t;
        kk[j] = k;
        valid[j] = (k < kend);
        loc[j] = valid[j] ? (idx[k] - base) : 0;
    }

    if (span <= LDS_FLOATS) {
        int nf4 = (span + 3) >> 2;
        int maxf4 = (n_pad - base) >> 2;          // clamp (n_pad % 4 edge safety)
        if (nf4 > maxf4) nf4 = maxf4;

        for (int c = 0; c < NCH; ++c) {
            const float4* src =
                reinterpret_cast<const float4*>(in + (size_t)c * n_pad + base);
            __syncthreads();                       // prev channel's reads done
            for (int i = t; i < nf4; i += BLOCK)
                reinterpret_cast<float4*>(lds)[i] = src[i];
            __syncthreads();

            float* dst = out + (size_t)c * n_kept;
#pragma unroll
            for (int j = 0; j < PER_T; ++j)
                if (valid[j]) dst[kk[j]] = lds[loc[j]];
        }
    } else {
        // Fallback (local density dip): direct gather, correctness-safe.
        for (int c = 0; c < NCH; ++c) {
            const float* src = in + (size_t)c * n_pad;
            float* dst = out + (size_t)c * n_kept;
#pragma unroll
            for (int j = 0; j < PER_T; ++j)
                if (valid[j]) dst[kk[j]] = src[(size_t)base + loc[j]];
        }
    }
}

extern "C" void kernel_launch(void* const* d_in, const int* in_sizes, int n_in,
                              void* d_out, int out_size, void* d_ws, size_t ws_size,
                              hipStream_t stream) {
    const float* in  = (const float*)d_in[0];
    const int*   idx = (const int*)d_in[1];
    float*       out = (float*)d_out;

    int n_kept = in_sizes[1];            // 1048576
    int n_pad  = in_sizes[0] / NCH;      // 2097152

    int grid = (n_kept + K_TILE - 1) / K_TILE;   // 1024
    octree_depad_lds<<<grid, BLOCK, 0, stream>>>(in, idx, out, n_kept, n_pad);
}

// Round 3
// 399.782 us; speedup vs baseline: 1.0030x; 1.0014x over previous
//
#include <hip/hip_runtime.h>

#define NCH 32
#define BLOCK 256
#define WAVES 4
#define PER_LANE 4
#define WAVE_K (64 * PER_LANE)   // 256 kept per wave
#define WSPAN 768                // floats per buffer; expected span ~512, >10 sigma slack

// out[c,k] = in[c, idx[k]], idx sorted ~50% dense.
// Wave-autonomous: each wave owns 256 consecutive kept indices, stages the
// covering contiguous span (~512 floats) into its PRIVATE LDS buffer with
// coalesced float4 loads, gathers from LDS, stores float4. No __syncthreads
// anywhere: per-wave LDS ops are in-order, so wave-synchronous is safe and
// the compiler can pipeline across the channel loop freely.
__global__ __launch_bounds__(BLOCK) void octree_depad_wave(
    const float* __restrict__ in,
    const int* __restrict__ idx,
    float* __restrict__ out,
    int n_kept, int n_pad) {
    __shared__ float lds[WAVES][2][WSPAN];

    const int lane = threadIdx.x & 63;
    const int wid  = threadIdx.x >> 6;
    const int gw   = blockIdx.x * WAVES + wid;
    const int wbase = gw * WAVE_K;
    if (wbase >= n_kept) return;
    const int kend  = min(wbase + WAVE_K, n_kept);
    const int klast = kend - 1;

    // Covering span (wave-uniform scalar loads).
    const int base4 = idx[wbase] & ~3;           // float4-aligned
    const int span  = idx[klast] - base4 + 1;

    // This lane's 4 consecutive kept positions.
    const int k = wbase + lane * PER_LANE;
    const bool any  = (k < kend);
    const bool full = (k + PER_LANE <= kend);
    int i0 = 0, i1 = 0, i2 = 0, i3 = 0;
    if (full) {
        int4 iv = *reinterpret_cast<const int4*>(idx + k);   // 16B coalesced
        i0 = iv.x; i1 = iv.y; i2 = iv.z; i3 = iv.w;
    } else if (any) {
        i0 = idx[k];
        i1 = (k + 1 < kend) ? idx[k + 1] : i0;
        i2 = (k + 2 < kend) ? idx[k + 2] : i0;
        i3 = (k + 3 < kend) ? idx[k + 3] : i0;
    }

    if (span <= WSPAN) {
        int nf4 = (span + 3) >> 2;
        const int cap = (n_pad - base4) >> 2;    // stay inside the buffer
        if (nf4 > cap) nf4 = cap;
        const int l0 = i0 - base4, l1 = i1 - base4,
                  l2 = i2 - base4, l3 = i3 - base4;

        for (int c = 0; c < NCH; ++c) {
            float* buf = lds[wid][c & 1];
            const float4* src =
                reinterpret_cast<const float4*>(in + (size_t)c * n_pad + base4);
            for (int i = lane; i < nf4; i += 64)       // coalesced 16B/lane
                reinterpret_cast<float4*>(buf)[i] = src[i];
            // wave-synchronous: same-wave LDS ops complete in order; the
            // compiler's lgkmcnt waits on the reads below cover the writes.
            if (any) {
                float4 o;
                o.x = buf[l0]; o.y = buf[l1]; o.z = buf[l2]; o.w = buf[l3];
                float* dst = out + (size_t)c * n_kept + k;
                if (full) {
                    *reinterpret_cast<float4*>(dst) = o;   // 16B coalesced
                } else {
                    dst[0] = o.x;
                    if (k + 1 < kend) dst[1] = o.y;
                    if (k + 2 < kend) dst[2] = o.z;
                }
            }
        }
    } else {
        // Fallback (local density dip beyond WSPAN): direct gather.
        for (int c = 0; c < NCH; ++c) {
            const float* src = in + (size_t)c * n_pad;
            float* dst = out + (size_t)c * n_kept;
            if (full) {
                float4 o;
                o.x = src[i0]; o.y = src[i1]; o.z = src[i2]; o.w = src[i3];
                *reinterpret_cast<float4*>(dst + k) = o;
            } else if (any) {
                dst[k] = src[i0];
                if (k + 1 < kend) dst[k + 1] = src[i1];
                if (k + 2 < kend) dst[k + 2] = src[i2];
            }
        }
    }
}

extern "C" void kernel_launch(void* const* d_in, const int* in_sizes, int n_in,
                              void* d_out, int out_size, void* d_ws, size_t ws_size,
                              hipStream_t stream) {
    const float* in  = (const float*)d_in[0];
    const int*   idx = (const int*)d_in[1];
    float*       out = (float*)d_out;

    int n_kept = in_sizes[1];            // 1048576
    int n_pad  = in_sizes[0] / NCH;      // 2097152

    int grid = (n_kept + WAVES * WAVE_K - 1) / (WAVES * WAVE_K);   // 1024
    octree_depad_wave<<<grid, BLOCK, 0, stream>>>(in, idx, out, n_kept, n_pad);
}